// Round 1
// baseline (98.184 us; speedup 1.0000x reference)
//
#include <hip/hip_runtime.h>
#include <hip/hip_bf16.h>
#include <math.h>

// Problem constants (reference: BATCH=2048, D=256, TEMP=0.5)
#define NB        2048
#define TWO_N     4096
#define DIM       256
#define EPS       1e-12f
#define NT1D      (TWO_N / 128)                 // 32 tile rows/cols
#define NTILES    (NT1D * (NT1D + 1) / 2)       // 528 upper-triangle tiles

typedef __attribute__((ext_vector_type(8))) short  bf16x8;   // 8 bf16 = 4 VGPRs
typedef __attribute__((ext_vector_type(4))) float  f32x4;    // MFMA C/D

// ---------------------------------------------------------------------------
// K1: one wave per PAIR r in [0,2048): L2-normalize emb_i[r] -> z[r] and
// emb_j[r] -> z[r+NB] (bf16), and write the fp32-exact positive dot
// pos[r] = <z_i, z_j>. Also zeroes den[4096] and the ticket counter.
// ---------------------------------------------------------------------------
__global__ __launch_bounds__(256) void nrm_kernel(
    const float* __restrict__ emb_i, const float* __restrict__ emb_j,
    __hip_bfloat16* __restrict__ zb, float* __restrict__ pos,
    float* __restrict__ den, unsigned int* __restrict__ ctr)
{
    int t = threadIdx.x;
    int wave = t >> 6, lane = t & 63;
    int r = blockIdx.x * 4 + wave;              // pair index 0..2047
    float4 a = ((const float4*)(emb_i + (size_t)r * DIM))[lane];
    float4 b = ((const float4*)(emb_j + (size_t)r * DIM))[lane];
    float sa = a.x*a.x + a.y*a.y + a.z*a.z + a.w*a.w;
    float sb = b.x*b.x + b.y*b.y + b.z*b.z + b.w*b.w;
    float sd = a.x*b.x + a.y*b.y + a.z*b.z + a.w*b.w;
    #pragma unroll
    for (int off = 32; off >= 1; off >>= 1) {
        sa += __shfl_xor(sa, off, 64);
        sb += __shfl_xor(sb, off, 64);
        sd += __shfl_xor(sd, off, 64);
    }
    float si = 1.0f / fmaxf(sqrtf(sa), EPS);
    float sj = 1.0f / fmaxf(sqrtf(sb), EPS);

    union { __hip_bfloat16 h[4]; uint2 u; } pk;
    pk.h[0] = __float2bfloat16(a.x * si);
    pk.h[1] = __float2bfloat16(a.y * si);
    pk.h[2] = __float2bfloat16(a.z * si);
    pk.h[3] = __float2bfloat16(a.w * si);
    ((uint2*)(zb + (size_t)r * DIM))[lane] = pk.u;
    pk.h[0] = __float2bfloat16(b.x * sj);
    pk.h[1] = __float2bfloat16(b.y * sj);
    pk.h[2] = __float2bfloat16(b.z * sj);
    pk.h[3] = __float2bfloat16(b.w * sj);
    ((uint2*)(zb + (size_t)(r + NB) * DIM))[lane] = pk.u;

    if (lane == 0) pos[r] = sd * si * sj;
    if (t < 8) den[blockIdx.x * 8 + t] = 0.0f;  // 512 blocks x 8 = 4096
    if (blockIdx.x == 0 && t == 0) *ctr = 0u;   // ticket counter (runs before K2)
}

// ---------------------------------------------------------------------------
// K2: den[r] += sum_j exp(2 * z_r . z_j) via bf16 MFMA, symmetric: 1-D grid
// of exactly the 528 upper-triangle 128x128 tiles (id = by*(by+1)/2 + bx).
// Off-diagonal blocks scatter both row-sums and col-sums into den.
// 4 waves in 2x2; wave tile 64x64 = 4x4 MFMA 16x16x32 accumulators.
// K-loop register double-buffered, fragments straight from L2 (no LDS).
// launch_bounds(256,3): 3 blocks/CU for latency hiding (VGPR cap 170).
// Fragment layouts (verified m89/m91): A[m=lane&15][k=quad*8+j],
// B[k=quad*8+j][n=lane&15], C/D: col=lane&15, row=quad*4+reg.
// NEW: last block (device-scope ticket) computes the final loss in-kernel,
// removing the former loss_kernel launch + one kernel-boundary drain.
// ---------------------------------------------------------------------------
__global__ __launch_bounds__(256, 3) void simexp_kernel(
    const __hip_bfloat16* __restrict__ zb, float* __restrict__ den,
    const float* __restrict__ pos, float* __restrict__ out,
    unsigned int* __restrict__ ctr)
{
    // Decode linear triangle index -> (bx, by), bx <= by.
    int id = blockIdx.x;
    int by = (int)((sqrtf(8.0f * (float)id + 1.0f) - 1.0f) * 0.5f);
    while ((by + 1) * (by + 2) / 2 <= id) ++by;   // fix float rounding
    while (by * (by + 1) / 2 > id) --by;
    int bx = id - by * (by + 1) / 2;

    const short* Z = (const short*)zb;
    int t = threadIdx.x;
    int w = t >> 6, lane = t & 63;
    int quad = lane >> 4, c16 = lane & 15;
    int wm = w >> 1, wn = w & 1;
    int rbase = bx * 128 + wm * 64;
    int jbase = by * 128 + wn * 64;

    const short* ap[4];
    const short* bp[4];
    #pragma unroll
    for (int mt = 0; mt < 4; ++mt)
        ap[mt] = Z + (size_t)(rbase + mt * 16 + c16) * DIM + quad * 8;
    #pragma unroll
    for (int nt = 0; nt < 4; ++nt)
        bp[nt] = Z + (size_t)(jbase + nt * 16 + c16) * DIM + quad * 8;

    f32x4 acc[4][4];
    #pragma unroll
    for (int mt = 0; mt < 4; ++mt)
        #pragma unroll
        for (int nt = 0; nt < 4; ++nt)
            acc[mt][nt] = (f32x4){0.f, 0.f, 0.f, 0.f};

    // Register double-buffered K loop: load kk+1 while MFMAing kk.
    bf16x8 af[2][4], bfv[2][4];
    #pragma unroll
    for (int mt = 0; mt < 4; ++mt) af[0][mt] = *(const bf16x8*)(ap[mt]);
    #pragma unroll
    for (int nt = 0; nt < 4; ++nt) bfv[0][nt] = *(const bf16x8*)(bp[nt]);

    #pragma unroll
    for (int kk = 0; kk < 8; ++kk) {
        int cur = kk & 1, nxt = cur ^ 1;
        if (kk < 7) {
            #pragma unroll
            for (int mt = 0; mt < 4; ++mt)
                af[nxt][mt] = *(const bf16x8*)(ap[mt] + (kk + 1) * 32);
            #pragma unroll
            for (int nt = 0; nt < 4; ++nt)
                bfv[nxt][nt] = *(const bf16x8*)(bp[nt] + (kk + 1) * 32);
        }
        #pragma unroll
        for (int mt = 0; mt < 4; ++mt)
            #pragma unroll
            for (int nt = 0; nt < 4; ++nt)
                acc[mt][nt] = __builtin_amdgcn_mfma_f32_16x16x32_bf16(
                    af[cur][mt], bfv[cur][nt], acc[mt][nt], 0, 0, 0);
    }

    // Epilogue. Row of acc[mt][nt][rg] = rbase+mt*16+quad*4+rg,
    // col = jbase+nt*16+c16.
    float rsum[4][4];
    #pragma unroll
    for (int mt = 0; mt < 4; ++mt)
        #pragma unroll
        for (int rg = 0; rg < 4; ++rg) rsum[mt][rg] = 0.f;

    if (bx == by) {
        // Diagonal block: mask r==j, row-sums only.
        #pragma unroll
        for (int mt = 0; mt < 4; ++mt) {
            #pragma unroll
            for (int nt = 0; nt < 4; ++nt) {
                int j = jbase + nt * 16 + c16;
                #pragma unroll
                for (int rg = 0; rg < 4; ++rg) {
                    int r = rbase + mt * 16 + quad * 4 + rg;
                    float e = __expf(2.0f * acc[mt][nt][rg]);
                    rsum[mt][rg] += (r == j) ? 0.f : e;
                }
            }
        }
    } else {
        // Off-diagonal: no diagonal possible; row-sums AND col-sums.
        float csum[4] = {0.f, 0.f, 0.f, 0.f};
        #pragma unroll
        for (int mt = 0; mt < 4; ++mt) {
            #pragma unroll
            for (int nt = 0; nt < 4; ++nt) {
                #pragma unroll
                for (int rg = 0; rg < 4; ++rg) {
                    float e = __expf(2.0f * acc[mt][nt][rg]);
                    rsum[mt][rg] += e;
                    csum[nt] += e;
                }
            }
        }
        // col c16 of tile nt: sum the 4 quads, atomic from quad 0.
        #pragma unroll
        for (int nt = 0; nt < 4; ++nt) {
            float v = csum[nt];
            v += __shfl_xor(v, 16, 64);
            v += __shfl_xor(v, 32, 64);
            if (quad == 0)
                atomicAdd(&den[jbase + nt * 16 + c16], v);
        }
    }

    // Row-sums: reduce the 16 col-lanes of each quad, atomic from c16==0.
    #pragma unroll
    for (int mt = 0; mt < 4; ++mt) {
        #pragma unroll
        for (int rg = 0; rg < 4; ++rg) {
            float v = rsum[mt][rg];
            v += __shfl_xor(v, 1, 64);
            v += __shfl_xor(v, 2, 64);
            v += __shfl_xor(v, 4, 64);
            v += __shfl_xor(v, 8, 64);
            if (c16 == 0)
                atomicAdd(&den[rbase + mt * 16 + quad * 4 + rg], v);
        }
    }

    // -----------------------------------------------------------------------
    // Ticket: last block to finish computes the loss (replaces loss_kernel).
    // -----------------------------------------------------------------------
    __shared__ int is_last;
    __shared__ float red[4];
    __syncthreads();                        // all block atomics issued
    if (t == 0) {
        __threadfence();                    // release our den updates (device)
        unsigned int old = atomicAdd(ctr, 1u);
        is_last = (old == (unsigned int)(NTILES - 1)) ? 1 : 0;
    }
    __syncthreads();
    if (is_last) {
        __threadfence();                    // acquire others' den updates
        float s = 0.f;
        for (int r = t; r < TWO_N; r += 256) {
            // Coherent read of atomically-accumulated den across XCD L2s:
            // device-scope RMW with identity (returns old value).
            float d = atomicAdd(&den[r], 0.0f);
            s += logf(d);
        }
        for (int p = t; p < NB; p += 256) s -= 4.0f * pos[p];
        #pragma unroll
        for (int off = 32; off >= 1; off >>= 1) s += __shfl_xor(s, off, 64);
        int wave = t >> 6, lane = t & 63;
        if (lane == 0) red[wave] = s;
        __syncthreads();
        if (t == 0)
            out[0] = (red[0] + red[1] + red[2] + red[3]) * (1.0f / (float)TWO_N);
    }
}

// ---------------------------------------------------------------------------
extern "C" void kernel_launch(void* const* d_in, const int* in_sizes, int n_in,
                              void* d_out, int out_size, void* d_ws, size_t ws_size,
                              hipStream_t stream)
{
    const float* emb_i = (const float*)d_in[0];
    const float* emb_j = (const float*)d_in[1];
    float* out = (float*)d_out;

    __hip_bfloat16* zb = (__hip_bfloat16*)d_ws;           // 4096*256 bf16 = 2 MB
    float* den = (float*)((char*)d_ws + (size_t)TWO_N * DIM * sizeof(__hip_bfloat16));
    float* pos = den + TWO_N;                             // 2048 f32
    unsigned int* ctr = (unsigned int*)(pos + NB);        // ticket counter

    nrm_kernel<<<NB / 4, 256, 0, stream>>>(emb_i, emb_j, zb, pos, den, ctr);
    simexp_kernel<<<NTILES, 256, 0, stream>>>(zb, den, pos, out, ctr);
}

// Round 2
// 88.787 us; speedup vs baseline: 1.1058x; 1.1058x over previous
//
#include <hip/hip_runtime.h>
#include <hip/hip_bf16.h>
#include <math.h>

// Problem constants (reference: BATCH=2048, D=256, TEMP=0.5)
#define NB        2048
#define TWO_N     4096
#define DIM       256
#define EPS       1e-12f
#define NT1D      (TWO_N / 128)                 // 32 tile rows/cols
#define NTILES    (NT1D * (NT1D + 1) / 2)       // 528 upper-triangle tiles

typedef __attribute__((ext_vector_type(8))) short  bf16x8;   // 8 bf16 = 4 VGPRs
typedef __attribute__((ext_vector_type(4))) float  f32x4;    // MFMA C/D

// ---------------------------------------------------------------------------
// K1: one wave per PAIR r in [0,2048): L2-normalize emb_i[r] -> z[r] and
// emb_j[r] -> z[r+NB] (bf16), and write the fp32-exact positive dot
// pos[r] = <z_i, z_j>. Also zeroes the scalar output accumulator.
// ---------------------------------------------------------------------------
__global__ __launch_bounds__(256) void nrm_kernel(
    const float* __restrict__ emb_i, const float* __restrict__ emb_j,
    __hip_bfloat16* __restrict__ zb, float* __restrict__ pos,
    float* __restrict__ out)
{
    int t = threadIdx.x;
    int wave = t >> 6, lane = t & 63;
    int r = blockIdx.x * 4 + wave;              // pair index 0..2047
    float4 a = ((const float4*)(emb_i + (size_t)r * DIM))[lane];
    float4 b = ((const float4*)(emb_j + (size_t)r * DIM))[lane];
    float sa = a.x*a.x + a.y*a.y + a.z*a.z + a.w*a.w;
    float sb = b.x*b.x + b.y*b.y + b.z*b.z + b.w*b.w;
    float sd = a.x*b.x + a.y*b.y + a.z*b.z + a.w*b.w;
    #pragma unroll
    for (int off = 32; off >= 1; off >>= 1) {
        sa += __shfl_xor(sa, off, 64);
        sb += __shfl_xor(sb, off, 64);
        sd += __shfl_xor(sd, off, 64);
    }
    float si = 1.0f / fmaxf(sqrtf(sa), EPS);
    float sj = 1.0f / fmaxf(sqrtf(sb), EPS);

    union { __hip_bfloat16 h[4]; uint2 u; } pk;
    pk.h[0] = __float2bfloat16(a.x * si);
    pk.h[1] = __float2bfloat16(a.y * si);
    pk.h[2] = __float2bfloat16(a.z * si);
    pk.h[3] = __float2bfloat16(a.w * si);
    ((uint2*)(zb + (size_t)r * DIM))[lane] = pk.u;
    pk.h[0] = __float2bfloat16(b.x * sj);
    pk.h[1] = __float2bfloat16(b.y * sj);
    pk.h[2] = __float2bfloat16(b.z * sj);
    pk.h[3] = __float2bfloat16(b.w * sj);
    ((uint2*)(zb + (size_t)(r + NB) * DIM))[lane] = pk.u;

    if (lane == 0) pos[r] = sd * si * sj;
    if (blockIdx.x == 0 && t == 0) out[0] = 0.0f;   // loss accumulator
}

// ---------------------------------------------------------------------------
// K2: bf16 MFMA over the 528 upper-triangle 128x128 tiles. NO atomics:
// each wave writes its row/col exp-sums into a private, collision-free slot
// part[stripe][row(0..127)][k(0..63)]:
//   row-sums of block (bx,by), wave col-half wn -> part[bx][j][2*by + wn]
//   col-sums of block (bx,by), wave row-half wm -> part[by][j][2*bx + wm]
// For stripe s: k in [0,2s) are col-contribs (bx<s), k in [2s,64) are
// row-contribs (by>=s) -> every slot written exactly once (no zeroing).
// k is the innermost dim (256 B per row) so the reducer reads contiguously.
// 4 waves in 2x2; wave tile 64x64 = 4x4 MFMA 16x16x32 accumulators.
// K-loop register double-buffered, fragments straight from L2 (no LDS).
// Fragment layouts (verified m89/m91): A[m=lane&15][k=quad*8+j],
// B[k=quad*8+j][n=lane&15], C/D: col=lane&15, row=quad*4+reg.
// ---------------------------------------------------------------------------
__global__ __launch_bounds__(256, 3) void simexp_kernel(
    const __hip_bfloat16* __restrict__ zb, float* __restrict__ part)
{
    // Decode linear triangle index -> (bx, by), bx <= by.
    int id = blockIdx.x;
    int by = (int)((sqrtf(8.0f * (float)id + 1.0f) - 1.0f) * 0.5f);
    while ((by + 1) * (by + 2) / 2 <= id) ++by;   // fix float rounding
    while (by * (by + 1) / 2 > id) --by;
    int bx = id - by * (by + 1) / 2;

    const short* Z = (const short*)zb;
    int t = threadIdx.x;
    int w = t >> 6, lane = t & 63;
    int quad = lane >> 4, c16 = lane & 15;
    int wm = w >> 1, wn = w & 1;
    int rbase = bx * 128 + wm * 64;
    int jbase = by * 128 + wn * 64;

    const short* ap[4];
    const short* bp[4];
    #pragma unroll
    for (int mt = 0; mt < 4; ++mt)
        ap[mt] = Z + (size_t)(rbase + mt * 16 + c16) * DIM + quad * 8;
    #pragma unroll
    for (int nt = 0; nt < 4; ++nt)
        bp[nt] = Z + (size_t)(jbase + nt * 16 + c16) * DIM + quad * 8;

    f32x4 acc[4][4];
    #pragma unroll
    for (int mt = 0; mt < 4; ++mt)
        #pragma unroll
        for (int nt = 0; nt < 4; ++nt)
            acc[mt][nt] = (f32x4){0.f, 0.f, 0.f, 0.f};

    // Register double-buffered K loop: load kk+1 while MFMAing kk.
    bf16x8 af[2][4], bfv[2][4];
    #pragma unroll
    for (int mt = 0; mt < 4; ++mt) af[0][mt] = *(const bf16x8*)(ap[mt]);
    #pragma unroll
    for (int nt = 0; nt < 4; ++nt) bfv[0][nt] = *(const bf16x8*)(bp[nt]);

    #pragma unroll
    for (int kk = 0; kk < 8; ++kk) {
        int cur = kk & 1, nxt = cur ^ 1;
        if (kk < 7) {
            #pragma unroll
            for (int mt = 0; mt < 4; ++mt)
                af[nxt][mt] = *(const bf16x8*)(ap[mt] + (kk + 1) * 32);
            #pragma unroll
            for (int nt = 0; nt < 4; ++nt)
                bfv[nxt][nt] = *(const bf16x8*)(bp[nt] + (kk + 1) * 32);
        }
        #pragma unroll
        for (int mt = 0; mt < 4; ++mt)
            #pragma unroll
            for (int nt = 0; nt < 4; ++nt)
                acc[mt][nt] = __builtin_amdgcn_mfma_f32_16x16x32_bf16(
                    af[cur][mt], bfv[cur][nt], acc[mt][nt], 0, 0, 0);
    }

    // Epilogue. Row of acc[mt][nt][rg] = rbase+mt*16+quad*4+rg,
    // col = jbase+nt*16+c16.
    float rsum[4][4];
    #pragma unroll
    for (int mt = 0; mt < 4; ++mt)
        #pragma unroll
        for (int rg = 0; rg < 4; ++rg) rsum[mt][rg] = 0.f;

    if (bx == by) {
        // Diagonal block: mask r==j, row-sums only.
        #pragma unroll
        for (int mt = 0; mt < 4; ++mt) {
            #pragma unroll
            for (int nt = 0; nt < 4; ++nt) {
                int j = jbase + nt * 16 + c16;
                #pragma unroll
                for (int rg = 0; rg < 4; ++rg) {
                    int r = rbase + mt * 16 + quad * 4 + rg;
                    float e = __expf(2.0f * acc[mt][nt][rg]);
                    rsum[mt][rg] += (r == j) ? 0.f : e;
                }
            }
        }
    } else {
        // Off-diagonal: no diagonal possible; row-sums AND col-sums.
        float csum[4] = {0.f, 0.f, 0.f, 0.f};
        #pragma unroll
        for (int mt = 0; mt < 4; ++mt) {
            #pragma unroll
            for (int nt = 0; nt < 4; ++nt) {
                #pragma unroll
                for (int rg = 0; rg < 4; ++rg) {
                    float e = __expf(2.0f * acc[mt][nt][rg]);
                    rsum[mt][rg] += e;
                    csum[nt] += e;
                }
            }
        }
        // col c16 of tile nt: sum the 4 quads; quad 0 writes its slot.
        #pragma unroll
        for (int nt = 0; nt < 4; ++nt) {
            float v = csum[nt];
            v += __shfl_xor(v, 16, 64);
            v += __shfl_xor(v, 32, 64);
            if (quad == 0)
                part[(size_t)(by * 128 + wn * 64 + nt * 16 + c16) * 64
                     + 2 * bx + wm] = v;
        }
    }

    // Row-sums: reduce the 16 col-lanes of each quad; c16==0 writes its slot.
    #pragma unroll
    for (int mt = 0; mt < 4; ++mt) {
        #pragma unroll
        for (int rg = 0; rg < 4; ++rg) {
            float v = rsum[mt][rg];
            v += __shfl_xor(v, 1, 64);
            v += __shfl_xor(v, 2, 64);
            v += __shfl_xor(v, 4, 64);
            v += __shfl_xor(v, 8, 64);
            if (c16 == 0)
                part[(size_t)(rbase + mt * 16 + quad * 4 + rg) * 64
                     + 2 * by + wn] = v;
        }
    }
}

// ---------------------------------------------------------------------------
// K3: 32 blocks x 128 threads. Block s, thread t owns row r = s*128+t:
// den_r = sum of its 64 partials (256 B contiguous), then
// loss_r = log(den_r) - 2*pos[r mod 2048]. Block-reduce, one atomicAdd of
// the scaled partial into out[0] (32 atomics total; out zeroed by K1).
// ---------------------------------------------------------------------------
__global__ __launch_bounds__(128) void redloss_kernel(
    const float* __restrict__ part, const float* __restrict__ pos,
    float* __restrict__ out)
{
    int s = blockIdx.x, t = threadIdx.x;
    int r = s * 128 + t;
    const float4* p = (const float4*)(part + ((size_t)r << 6));
    float sum = 0.f;
    #pragma unroll
    for (int i = 0; i < 16; ++i) {
        float4 v = p[i];
        sum += v.x + v.y + v.z + v.w;
    }
    float val = logf(sum) - 2.0f * pos[r & (NB - 1)];
    #pragma unroll
    for (int off = 32; off >= 1; off >>= 1) val += __shfl_xor(val, off, 64);
    __shared__ float red[2];
    if ((t & 63) == 0) red[t >> 6] = val;
    __syncthreads();
    if (t == 0)
        atomicAdd(out, (red[0] + red[1]) * (1.0f / (float)TWO_N));
}

// ---------------------------------------------------------------------------
extern "C" void kernel_launch(void* const* d_in, const int* in_sizes, int n_in,
                              void* d_out, int out_size, void* d_ws, size_t ws_size,
                              hipStream_t stream)
{
    const float* emb_i = (const float*)d_in[0];
    const float* emb_j = (const float*)d_in[1];
    float* out = (float*)d_out;

    __hip_bfloat16* zb = (__hip_bfloat16*)d_ws;           // 4096*256 bf16 = 2 MB
    float* part = (float*)((char*)d_ws + (size_t)TWO_N * DIM * sizeof(__hip_bfloat16));
    // part: 4096 rows x 64 partials = 1 MB
    float* pos = part + (size_t)TWO_N * 64;               // 2048 f32

    nrm_kernel<<<NB / 4, 256, 0, stream>>>(emb_i, emb_j, zb, pos, out);
    simexp_kernel<<<NTILES, 256, 0, stream>>>(zb, part);
    redloss_kernel<<<NT1D, 128, 0, stream>>>(part, pos, out);
}

// Round 3
// 88.571 us; speedup vs baseline: 1.1085x; 1.0024x over previous
//
#include <hip/hip_runtime.h>
#include <hip/hip_bf16.h>
#include <math.h>

// Problem constants (reference: BATCH=2048, D=256, TEMP=0.5)
#define NB        2048
#define TWO_N     4096
#define DIM       256
#define EPS       1e-12f
#define NT1D      (TWO_N / 128)                 // 32 tile rows/cols
#define NTILES    (NT1D * (NT1D + 1) / 2)       // 528 upper-triangle tiles

typedef __attribute__((ext_vector_type(8))) short  bf16x8;   // 8 bf16 = 4 VGPRs
typedef __attribute__((ext_vector_type(4))) float  f32x4;    // MFMA C/D

// ---------------------------------------------------------------------------
// K1: one wave per PAIR r in [0,2048): L2-normalize emb_i[r] -> z[r] and
// emb_j[r] -> z[r+NB] (bf16), and write the fp32-exact positive dot
// pos[r] = <z_i, z_j>. Also zeroes the scalar output accumulator.
// ---------------------------------------------------------------------------
__global__ __launch_bounds__(256) void nrm_kernel(
    const float* __restrict__ emb_i, const float* __restrict__ emb_j,
    __hip_bfloat16* __restrict__ zb, float* __restrict__ pos,
    float* __restrict__ out)
{
    int t = threadIdx.x;
    int wave = t >> 6, lane = t & 63;
    int r = blockIdx.x * 4 + wave;              // pair index 0..2047
    float4 a = ((const float4*)(emb_i + (size_t)r * DIM))[lane];
    float4 b = ((const float4*)(emb_j + (size_t)r * DIM))[lane];
    float sa = a.x*a.x + a.y*a.y + a.z*a.z + a.w*a.w;
    float sb = b.x*b.x + b.y*b.y + b.z*b.z + b.w*b.w;
    float sd = a.x*b.x + a.y*b.y + a.z*b.z + a.w*b.w;
    #pragma unroll
    for (int off = 32; off >= 1; off >>= 1) {
        sa += __shfl_xor(sa, off, 64);
        sb += __shfl_xor(sb, off, 64);
        sd += __shfl_xor(sd, off, 64);
    }
    float si = 1.0f / fmaxf(sqrtf(sa), EPS);
    float sj = 1.0f / fmaxf(sqrtf(sb), EPS);

    union { __hip_bfloat16 h[4]; uint2 u; } pk;
    pk.h[0] = __float2bfloat16(a.x * si);
    pk.h[1] = __float2bfloat16(a.y * si);
    pk.h[2] = __float2bfloat16(a.z * si);
    pk.h[3] = __float2bfloat16(a.w * si);
    ((uint2*)(zb + (size_t)r * DIM))[lane] = pk.u;
    pk.h[0] = __float2bfloat16(b.x * sj);
    pk.h[1] = __float2bfloat16(b.y * sj);
    pk.h[2] = __float2bfloat16(b.z * sj);
    pk.h[3] = __float2bfloat16(b.w * sj);
    ((uint2*)(zb + (size_t)(r + NB) * DIM))[lane] = pk.u;

    if (lane == 0) pos[r] = sd * si * sj;
    if (blockIdx.x == 0 && t == 0) out[0] = 0.0f;   // loss accumulator
}

// ---------------------------------------------------------------------------
// K2: bf16 MFMA over the 528 upper-triangle 128x128 tiles. NO atomics:
// each wave writes its row/col exp-sums into a private, collision-free slot
// part[stripe][row(0..127)][k(0..63)]:
//   row-sums of block (bx,by), wave col-half wn -> part[bx][j][2*by + wn]
//   col-sums of block (bx,by), wave row-half wm -> part[by][j][2*bx + wm]
// Every slot written exactly once (no zeroing needed).
// K-loop: fully hand-pipelined depth-2 with NAMED fragment registers — no
// arrays, no runtime-flavored indices, so nothing can be demoted off the
// register file (round-2's VGPR_Count=72 showed the af[2][4]/bfv[2][4]
// double-buffer was demoted -> serial full-latency loads -> ~34us stall).
// Fragment layouts (verified m89/m91): A[m=lane&15][k=quad*8+j],
// B[k=quad*8+j][n=lane&15], C/D: col=lane&15, row=quad*4+reg.
// ---------------------------------------------------------------------------
#define MFMA1(Av, Bv, m, n) \
    acc[m][n] = __builtin_amdgcn_mfma_f32_16x16x32_bf16(Av, Bv, acc[m][n], 0, 0, 0);

#define MFMA_ROW(Av, B0v, B1v, B2v, B3v, m) \
    MFMA1(Av, B0v, m, 0) MFMA1(Av, B1v, m, 1) \
    MFMA1(Av, B2v, m, 2) MFMA1(Av, B3v, m, 3)

#define MMSTEP(A0v, A1v, A2v, A3v, B0v, B1v, B2v, B3v) \
    MFMA_ROW(A0v, B0v, B1v, B2v, B3v, 0) \
    MFMA_ROW(A1v, B0v, B1v, B2v, B3v, 1) \
    MFMA_ROW(A2v, B0v, B1v, B2v, B3v, 2) \
    MFMA_ROW(A3v, B0v, B1v, B2v, B3v, 3)

#define LDSET(dA0, dA1, dA2, dA3, dB0, dB1, dB2, dB3, s) \
    dA0 = *(const bf16x8*)(apt0 + (s) * 32); \
    dA1 = *(const bf16x8*)(apt1 + (s) * 32); \
    dA2 = *(const bf16x8*)(apt2 + (s) * 32); \
    dA3 = *(const bf16x8*)(apt3 + (s) * 32); \
    dB0 = *(const bf16x8*)(bpt0 + (s) * 32); \
    dB1 = *(const bf16x8*)(bpt1 + (s) * 32); \
    dB2 = *(const bf16x8*)(bpt2 + (s) * 32); \
    dB3 = *(const bf16x8*)(bpt3 + (s) * 32);

__global__ __launch_bounds__(256, 3) void simexp_kernel(
    const __hip_bfloat16* __restrict__ zb, float* __restrict__ part)
{
    // Decode linear triangle index -> (bx, by), bx <= by.
    int id = blockIdx.x;
    int by = (int)((sqrtf(8.0f * (float)id + 1.0f) - 1.0f) * 0.5f);
    while ((by + 1) * (by + 2) / 2 <= id) ++by;   // fix float rounding
    while (by * (by + 1) / 2 > id) --by;
    int bx = id - by * (by + 1) / 2;

    const short* Z = (const short*)zb;
    int t = threadIdx.x;
    int w = t >> 6, lane = t & 63;
    int quad = lane >> 4, c16 = lane & 15;
    int wm = w >> 1, wn = w & 1;
    int rbase = bx * 128 + wm * 64;
    int jbase = by * 128 + wn * 64;

    const short* apt0 = Z + (size_t)(rbase +  0 + c16) * DIM + quad * 8;
    const short* apt1 = Z + (size_t)(rbase + 16 + c16) * DIM + quad * 8;
    const short* apt2 = Z + (size_t)(rbase + 32 + c16) * DIM + quad * 8;
    const short* apt3 = Z + (size_t)(rbase + 48 + c16) * DIM + quad * 8;
    const short* bpt0 = Z + (size_t)(jbase +  0 + c16) * DIM + quad * 8;
    const short* bpt1 = Z + (size_t)(jbase + 16 + c16) * DIM + quad * 8;
    const short* bpt2 = Z + (size_t)(jbase + 32 + c16) * DIM + quad * 8;
    const short* bpt3 = Z + (size_t)(jbase + 48 + c16) * DIM + quad * 8;

    f32x4 acc[4][4];
    #pragma unroll
    for (int mt = 0; mt < 4; ++mt)
        #pragma unroll
        for (int nt = 0; nt < 4; ++nt)
            acc[mt][nt] = (f32x4){0.f, 0.f, 0.f, 0.f};

    // Hand-written depth-2 software pipeline over the 8 K-steps.
    bf16x8 A0, A1, A2, A3, B0, B1, B2, B3;   // even steps
    bf16x8 P0, P1, P2, P3, Q0, Q1, Q2, Q3;   // odd steps

    LDSET(A0, A1, A2, A3, B0, B1, B2, B3, 0)
    LDSET(P0, P1, P2, P3, Q0, Q1, Q2, Q3, 1)
    MMSTEP(A0, A1, A2, A3, B0, B1, B2, B3)            // kk=0
    LDSET(A0, A1, A2, A3, B0, B1, B2, B3, 2)
    MMSTEP(P0, P1, P2, P3, Q0, Q1, Q2, Q3)            // kk=1
    LDSET(P0, P1, P2, P3, Q0, Q1, Q2, Q3, 3)
    MMSTEP(A0, A1, A2, A3, B0, B1, B2, B3)            // kk=2
    LDSET(A0, A1, A2, A3, B0, B1, B2, B3, 4)
    MMSTEP(P0, P1, P2, P3, Q0, Q1, Q2, Q3)            // kk=3
    LDSET(P0, P1, P2, P3, Q0, Q1, Q2, Q3, 5)
    MMSTEP(A0, A1, A2, A3, B0, B1, B2, B3)            // kk=4
    LDSET(A0, A1, A2, A3, B0, B1, B2, B3, 6)
    MMSTEP(P0, P1, P2, P3, Q0, Q1, Q2, Q3)            // kk=5
    LDSET(P0, P1, P2, P3, Q0, Q1, Q2, Q3, 7)
    MMSTEP(A0, A1, A2, A3, B0, B1, B2, B3)            // kk=6
    MMSTEP(P0, P1, P2, P3, Q0, Q1, Q2, Q3)            // kk=7

    // Epilogue. Row of acc[mt][nt][rg] = rbase+mt*16+quad*4+rg,
    // col = jbase+nt*16+c16.
    float rsum[4][4];
    #pragma unroll
    for (int mt = 0; mt < 4; ++mt)
        #pragma unroll
        for (int rg = 0; rg < 4; ++rg) rsum[mt][rg] = 0.f;

    if (bx == by) {
        // Diagonal block: mask r==j, row-sums only.
        #pragma unroll
        for (int mt = 0; mt < 4; ++mt) {
            #pragma unroll
            for (int nt = 0; nt < 4; ++nt) {
                int j = jbase + nt * 16 + c16;
                #pragma unroll
                for (int rg = 0; rg < 4; ++rg) {
                    int r = rbase + mt * 16 + quad * 4 + rg;
                    float e = __expf(2.0f * acc[mt][nt][rg]);
                    rsum[mt][rg] += (r == j) ? 0.f : e;
                }
            }
        }
    } else {
        // Off-diagonal: no diagonal possible; row-sums AND col-sums.
        float csum[4] = {0.f, 0.f, 0.f, 0.f};
        #pragma unroll
        for (int mt = 0; mt < 4; ++mt) {
            #pragma unroll
            for (int nt = 0; nt < 4; ++nt) {
                #pragma unroll
                for (int rg = 0; rg < 4; ++rg) {
                    float e = __expf(2.0f * acc[mt][nt][rg]);
                    rsum[mt][rg] += e;
                    csum[nt] += e;
                }
            }
        }
        // col c16 of tile nt: sum the 4 quads; quad 0 writes its slot.
        #pragma unroll
        for (int nt = 0; nt < 4; ++nt) {
            float v = csum[nt];
            v += __shfl_xor(v, 16, 64);
            v += __shfl_xor(v, 32, 64);
            if (quad == 0)
                part[(size_t)(by * 128 + wn * 64 + nt * 16 + c16) * 64
                     + 2 * bx + wm] = v;
        }
    }

    // Row-sums: reduce the 16 col-lanes of each quad; c16==0 writes its slot.
    #pragma unroll
    for (int mt = 0; mt < 4; ++mt) {
        #pragma unroll
        for (int rg = 0; rg < 4; ++rg) {
            float v = rsum[mt][rg];
            v += __shfl_xor(v, 1, 64);
            v += __shfl_xor(v, 2, 64);
            v += __shfl_xor(v, 4, 64);
            v += __shfl_xor(v, 8, 64);
            if (c16 == 0)
                part[(size_t)(rbase + mt * 16 + quad * 4 + rg) * 64
                     + 2 * by + wn] = v;
        }
    }
}

// ---------------------------------------------------------------------------
// K3: 32 blocks x 128 threads. Block s, thread t owns row r = s*128+t:
// den_r = sum of its 64 partials (256 B contiguous), then
// loss_r = log(den_r) - 2*pos[r mod 2048]. Block-reduce, one atomicAdd of
// the scaled partial into out[0] (32 atomics total; out zeroed by K1).
// ---------------------------------------------------------------------------
__global__ __launch_bounds__(128) void redloss_kernel(
    const float* __restrict__ part, const float* __restrict__ pos,
    float* __restrict__ out)
{
    int s = blockIdx.x, t = threadIdx.x;
    int r = s * 128 + t;
    const float4* p = (const float4*)(part + ((size_t)r << 6));
    float sum = 0.f;
    #pragma unroll
    for (int i = 0; i < 16; ++i) {
        float4 v = p[i];
        sum += v.x + v.y + v.z + v.w;
    }
    float val = logf(sum) - 2.0f * pos[r & (NB - 1)];
    #pragma unroll
    for (int off = 32; off >= 1; off >>= 1) val += __shfl_xor(val, off, 64);
    __shared__ float red[2];
    if ((t & 63) == 0) red[t >> 6] = val;
    __syncthreads();
    if (t == 0)
        atomicAdd(out, (red[0] + red[1]) * (1.0f / (float)TWO_N));
}

// ---------------------------------------------------------------------------
extern "C" void kernel_launch(void* const* d_in, const int* in_sizes, int n_in,
                              void* d_out, int out_size, void* d_ws, size_t ws_size,
                              hipStream_t stream)
{
    const float* emb_i = (const float*)d_in[0];
    const float* emb_j = (const float*)d_in[1];
    float* out = (float*)d_out;

    __hip_bfloat16* zb = (__hip_bfloat16*)d_ws;           // 4096*256 bf16 = 2 MB
    float* part = (float*)((char*)d_ws + (size_t)TWO_N * DIM * sizeof(__hip_bfloat16));
    // part: 4096 rows x 64 partials = 1 MB
    float* pos = part + (size_t)TWO_N * 64;               // 2048 f32

    nrm_kernel<<<NB / 4, 256, 0, stream>>>(emb_i, emb_j, zb, pos, out);
    simexp_kernel<<<NTILES, 256, 0, stream>>>(zb, part);
    redloss_kernel<<<NT1D, 128, 0, stream>>>(part, pos, out);
}